// Round 4
// baseline (10859.369 us; speedup 1.0000x reference)
//
#include <hip/hip_runtime.h>
#include <math.h>
#include <stdint.h>

#define B 1024
#define H 512
#define T_SRC 50
#define T_TGT 30
#define I_DIM 4

#define NTHR 256
#define NBLK 512
#define NGRP 16
#define GRP_BLKS 32
#define NBAR (2 * (T_SRC + T_TGT))   // 160 group barriers

typedef _Float16 half8 __attribute__((ext_vector_type(8)));
typedef float f32x4 __attribute__((ext_vector_type(4)));

#define GLOBAL_AS __attribute__((address_space(1)))
#define LDS_AS    __attribute__((address_space(3)))

__device__ __forceinline__ float sigm(float x) { return 1.0f / (1.0f + expf(-x)); }

struct KParams {
    const float* x;
    const float* eWih0; const float* eb0; const float* eb1;
    const float* dWih0; const float* db0; const float* db1;
    const float* headW; const float* headb;
    const _Float16* eWhh0; const _Float16* eWih1; const _Float16* eWhh1;
    const _Float16* dWhh0; const _Float16* dWih1; const _Float16* dWhh1;
    float* c0; float* c1;
    _Float16* h0a; _Float16* h0b; _Float16* h1a; _Float16* h1b;
    uint32_t* cnt;       // [NBAR][NGRP], zeroed each call
    float* outp;         // (B, T_TGT, 4)
};

// Per-group barrier: release fence -> arrive -> poll (agent-scope) -> acquire fence.
// Requires all GRP_BLKS blocks of the group to be co-resident (512 blocks, 4/CU capacity).
__device__ __forceinline__ void grp_barrier(uint32_t* cnt)
{
    __syncthreads();   // all block's mem ops drained before release
    if (threadIdx.x == 0) {
        __threadfence();   // agent release: push h/c stores to coherence point
        __hip_atomic_fetch_add(cnt, 1u, __ATOMIC_RELEASE, __HIP_MEMORY_SCOPE_AGENT);
        while (__hip_atomic_load(cnt, __ATOMIC_RELAXED, __HIP_MEMORY_SCOPE_AGENT) < GRP_BLKS)
            __builtin_amdgcn_s_sleep(2);
        __threadfence();   // agent acquire: invalidate stale L1/L2
    }
    __syncthreads();
}

// GEMM (64 batch x 64 gate-cols, K=512*npass) + LSTM cell. Verified round-2 core.
__device__ __forceinline__ void layer_step(
    char* __restrict__ smem,
    const _Float16* __restrict__ A1, const _Float16* __restrict__ W1,
    const _Float16* __restrict__ A2, const _Float16* __restrict__ W2,
    int npass,
    const float* __restrict__ xg, int xstride,   // global x rows (or null)
    const float* __restrict__ xl,                // LDS dec values (or null)
    const float* __restrict__ Wih,
    const float* __restrict__ bias,
    float* __restrict__ c_st, _Float16* __restrict__ h_out,
    int m0, int kc0,
    const size_t* __restrict__ aoff, const size_t* __restrict__ boff)
{
    const int tid = threadIdx.x;
    const int w = tid >> 6, l = tid & 63;
    const int mw = (w & 1) * 32;
    const int nw = (w >> 1) * 32;

    f32x4 acc[2][2] = {};
    const int nt = npass * 8;

    auto stage = [&](int t, int cur) {
        const _Float16* Ap = (t < 8) ? A1 : A2;
        const _Float16* Wp = (t < 8) ? W1 : W2;
        const int koff = (t & 7) * 64;
        char* dbase = smem + cur * 16384;
#pragma unroll
        for (int q = 0; q < 2; ++q) {
            __builtin_amdgcn_global_load_lds(
                (const GLOBAL_AS uint32_t*)(Ap + aoff[q] + koff),
                (LDS_AS uint32_t*)(dbase + (w * 2 + q) * 1024), 16, 0, 0);
            __builtin_amdgcn_global_load_lds(
                (const GLOBAL_AS uint32_t*)(Wp + boff[q] + koff),
                (LDS_AS uint32_t*)(dbase + 8192 + (w * 2 + q) * 1024), 16, 0, 0);
        }
    };

    stage(0, 0);
    __syncthreads();
    int cur = 0;
    for (int t = 0; t < nt; ++t) {
        if (t + 1 < nt) stage(t + 1, cur ^ 1);
        const char* ab = smem + cur * 16384;
        const char* bb = ab + 8192;
#pragma unroll
        for (int ks = 0; ks < 2; ++ks) {
            half8 af[2], bf[2];
#pragma unroll
            for (int f = 0; f < 2; ++f) {
                const int gg = ks * 4 + (l >> 4);
                const int m = mw + f * 16 + (l & 15);
                af[f] = *reinterpret_cast<const half8*>(ab + m * 128 + ((gg ^ (m & 7)) * 16));
                const int n = nw + f * 16 + (l & 15);
                bf[f] = *reinterpret_cast<const half8*>(bb + n * 128 + ((gg ^ (n & 7)) * 16));
            }
#pragma unroll
            for (int fm = 0; fm < 2; ++fm)
#pragma unroll
                for (int fn = 0; fn < 2; ++fn)
                    acc[fm][fn] = __builtin_amdgcn_mfma_f32_16x16x32_f16(
                        af[fm], bf[fn], acc[fm][fn], 0, 0, 0);
        }
        __syncthreads();
        cur ^= 1;
    }

    float* Gs = reinterpret_cast<float*>(smem);
#pragma unroll
    for (int fm = 0; fm < 2; ++fm)
#pragma unroll
        for (int fn = 0; fn < 2; ++fn)
#pragma unroll
            for (int r = 0; r < 4; ++r)
                Gs[(mw + fm * 16 + (l >> 4) * 4 + r) * 65 + nw + fn * 16 + (l & 15)] =
                    acc[fm][fn][r];
    __syncthreads();

#pragma unroll
    for (int it = 0; it < 4; ++it) {
        int id = it * NTHR + tid;
        int m = id >> 4, kc = id & 15;
        int brow = m0 + m;
        int k = kc0 + kc;
        float gi = Gs[m * 65 + 0 * 16 + kc] + bias[0 * H + k];
        float gf = Gs[m * 65 + 1 * 16 + kc] + bias[1 * H + k];
        float gg = Gs[m * 65 + 2 * 16 + kc] + bias[2 * H + k];
        float go = Gs[m * 65 + 3 * 16 + kc] + bias[3 * H + k];
        if (Wih != nullptr) {
            float x0, x1, x2, x3;
            if (xl != nullptr) {
                const float* xr = xl + m * 4;
                x0 = xr[0]; x1 = xr[1]; x2 = xr[2]; x3 = xr[3];
            } else {
                const float* xr = xg + (size_t)brow * xstride;
                x0 = xr[0]; x1 = xr[1]; x2 = xr[2]; x3 = xr[3];
            }
            const float* wi = &Wih[(size_t)(0 * H + k) * 4];
            const float* wf = &Wih[(size_t)(1 * H + k) * 4];
            const float* wg = &Wih[(size_t)(2 * H + k) * 4];
            const float* wo = &Wih[(size_t)(3 * H + k) * 4];
            gi += x0 * wi[0] + x1 * wi[1] + x2 * wi[2] + x3 * wi[3];
            gf += x0 * wf[0] + x1 * wf[1] + x2 * wf[2] + x3 * wf[3];
            gg += x0 * wg[0] + x1 * wg[1] + x2 * wg[2] + x3 * wg[3];
            go += x0 * wo[0] + x1 * wo[1] + x2 * wo[2] + x3 * wo[3];
        }
        size_t idx = (size_t)brow * H + k;
        float c_old = c_st[idx];
        float c_new = sigm(gf) * c_old + sigm(gi) * tanhf(gg);
        c_st[idx] = c_new;
        h_out[idx] = (_Float16)(sigm(go) * tanhf(c_new));
    }
}

// head: decb[row][o] = h1[m0+row,:] . headW[o,:] + headb[o]; ntile0 writes d_out
__device__ __forceinline__ void head_phase(
    const _Float16* __restrict__ h1, const float* __restrict__ headW,
    const float* __restrict__ headb, float* __restrict__ decb,
    float* __restrict__ outp, int m0, int t)
{
    const int tid = threadIdx.x;
    const int row = tid >> 2, o = tid & 3;
    const _Float16* hr = h1 + (size_t)(m0 + row) * H;
    const float* wr = headW + o * H;
    float s = 0.f;
    for (int k = 0; k < H; k += 8) {
        half8 hv = *reinterpret_cast<const half8*>(hr + k);
#pragma unroll
        for (int j = 0; j < 8; ++j) s += (float)hv[j] * wr[k + j];
    }
    s += headb[o];
    decb[row * 4 + o] = s;
    if (outp != nullptr)
        outp[((size_t)(m0 + row) * T_TGT + t) * I_DIM + o] = s;
}

__global__ __launch_bounds__(NTHR, 2)
void lstm_persist(KParams P)
{
    __shared__ __align__(16) char smem[32768];
    __shared__ float decbuf[64 * 4];

    const int bx = blockIdx.x;
    // bx -> (group, ntile): CU-sharing blocks (bx, bx+256) land in different groups;
    // same XCD keeps a fixed hidden slice (weights stay L2-warm between invalidates).
    const int sxcd = bx & 7;
    const int q = bx >> 3;               // 0..63
    const int lowq = q & 15;
    const int hi = (q >> 4) & 3;
    const int g = lowq ^ ((hi >> 1) << 3);
    const int ntile = sxcd * 4 + hi;
    const int m0 = g * 64;
    const int kc0 = ntile * 16;

    // staging offsets (verified round-2 mapping)
    const int tid = threadIdx.x;
    const int w = tid >> 6, l = tid & 63;
    size_t aoff[2], boff[2];
#pragma unroll
    for (int qq = 0; qq < 2; ++qq) {
        int rowq = (w * 2 + qq) * 8 + (l >> 3);
        int gsrc = (l & 7) ^ (rowq & 7);
        aoff[qq] = (size_t)(m0 + rowq) * H + gsrc * 8;
        int jg = (rowq >> 4) * H + kc0 + (rowq & 15);
        boff[qq] = (size_t)jg * H + gsrc * 8;
    }

    _Float16* h0[2] = {P.h0a, P.h0b};
    _Float16* h1[2] = {P.h1a, P.h1b};
    int p = 0, bar = 0;

    for (int t = 0; t < T_SRC; ++t) {
        layer_step(smem, h0[p], P.eWhh0, nullptr, nullptr, 1,
                   P.x + (size_t)t * I_DIM, T_SRC * I_DIM, nullptr,
                   P.eWih0, P.eb0, P.c0, h0[1 - p], m0, kc0, aoff, boff);
        grp_barrier(&P.cnt[(size_t)(bar++) * NGRP + g]);
        layer_step(smem, h0[1 - p], P.eWih1, h1[p], P.eWhh1, 2,
                   nullptr, 0, nullptr, nullptr, P.eb1, P.c1, h1[1 - p],
                   m0, kc0, aoff, boff);
        grp_barrier(&P.cnt[(size_t)(bar++) * NGRP + g]);
        p ^= 1;
    }

    for (int t = 0; t < T_TGT; ++t) {
        const float* xg = (t == 0) ? (P.x + (size_t)(T_SRC - 1) * I_DIM) : nullptr;
        const float* xl = (t == 0) ? nullptr : decbuf;
        layer_step(smem, h0[p], P.dWhh0, nullptr, nullptr, 1,
                   xg, T_SRC * I_DIM, xl, P.dWih0, P.db0, P.c0, h0[1 - p],
                   m0, kc0, aoff, boff);
        grp_barrier(&P.cnt[(size_t)(bar++) * NGRP + g]);
        layer_step(smem, h0[1 - p], P.dWih1, h1[p], P.dWhh1, 2,
                   nullptr, 0, nullptr, nullptr, P.db1, P.c1, h1[1 - p],
                   m0, kc0, aoff, boff);
        grp_barrier(&P.cnt[(size_t)(bar++) * NGRP + g]);
        head_phase(h1[1 - p], P.headW, P.headb, decbuf,
                   (ntile == 0) ? P.outp : nullptr, m0, t);
        __syncthreads();
        p ^= 1;
    }
}

__global__ void zero_kernel(float* __restrict__ ptr, int n)
{
    int i = blockIdx.x * blockDim.x + threadIdx.x;
    int stride = gridDim.x * blockDim.x;
    for (; i < n; i += stride) ptr[i] = 0.f;
}

__global__ void f32_to_f16(const float* __restrict__ src, _Float16* __restrict__ dst, int n)
{
    int i = blockIdx.x * blockDim.x + threadIdx.x;
    int stride = gridDim.x * blockDim.x;
    for (; i < n; i += stride) dst[i] = (_Float16)src[i];
}

extern "C" void kernel_launch(void* const* d_in, const int* in_sizes, int n_in,
                              void* d_out, int out_size, void* d_ws, size_t ws_size,
                              hipStream_t stream)
{
    const float* x        = (const float*)d_in[0];
    const float* enc_Wih0 = (const float*)d_in[1];
    const float* enc_Whh0 = (const float*)d_in[2];
    const float* enc_b0   = (const float*)d_in[3];
    const float* enc_Wih1 = (const float*)d_in[4];
    const float* enc_Whh1 = (const float*)d_in[5];
    const float* enc_b1   = (const float*)d_in[6];
    const float* dec_Wih0 = (const float*)d_in[7];
    const float* dec_Whh0 = (const float*)d_in[8];
    const float* dec_b0   = (const float*)d_in[9];
    const float* dec_Wih1 = (const float*)d_in[10];
    const float* dec_Whh1 = (const float*)d_in[11];
    const float* dec_b1   = (const float*)d_in[12];
    const float* head_W   = (const float*)d_in[13];
    const float* head_b   = (const float*)d_in[14];

    const size_t MB = 1u << 20;
    char* ws = (char*)d_ws;
    float*    c0     = (float*)(ws + 0 * MB);   // 2MB
    float*    c1     = (float*)(ws + 2 * MB);   // 2MB
    _Float16* h0a    = (_Float16*)(ws + 4 * MB);
    _Float16* h0b    = (_Float16*)(ws + 5 * MB);
    _Float16* h1a    = (_Float16*)(ws + 6 * MB);
    _Float16* h1b    = (_Float16*)(ws + 7 * MB);
    uint32_t* cnt    = (uint32_t*)(ws + 8 * MB);   // 160*16*4 = 10 KB
    _Float16* eWhh0f = (_Float16*)(ws + 9 * MB);
    _Float16* eWih1f = (_Float16*)(ws + 11 * MB);
    _Float16* eWhh1f = (_Float16*)(ws + 13 * MB);
    _Float16* dWhh0f = (_Float16*)(ws + 15 * MB);
    _Float16* dWih1f = (_Float16*)(ws + 17 * MB);
    _Float16* dWhh1f = (_Float16*)(ws + 19 * MB);

    const int WN = 4 * H * H;

    // zero c/h buffers + barrier counters (8MB + 16KB)
    zero_kernel<<<2048, 256, 0, stream>>>((float*)ws, (int)((8 * MB + 16384) / 4));
    f32_to_f16<<<1024, 256, 0, stream>>>(enc_Whh0, eWhh0f, WN);
    f32_to_f16<<<1024, 256, 0, stream>>>(enc_Wih1, eWih1f, WN);
    f32_to_f16<<<1024, 256, 0, stream>>>(enc_Whh1, eWhh1f, WN);
    f32_to_f16<<<1024, 256, 0, stream>>>(dec_Whh0, dWhh0f, WN);
    f32_to_f16<<<1024, 256, 0, stream>>>(dec_Wih1, dWih1f, WN);
    f32_to_f16<<<1024, 256, 0, stream>>>(dec_Whh1, dWhh1f, WN);

    KParams P;
    P.x = x;
    P.eWih0 = enc_Wih0; P.eb0 = enc_b0; P.eb1 = enc_b1;
    P.dWih0 = dec_Wih0; P.db0 = dec_b0; P.db1 = dec_b1;
    P.headW = head_W; P.headb = head_b;
    P.eWhh0 = eWhh0f; P.eWih1 = eWih1f; P.eWhh1 = eWhh1f;
    P.dWhh0 = dWhh0f; P.dWih1 = dWih1f; P.dWhh1 = dWhh1f;
    P.c0 = c0; P.c1 = c1;
    P.h0a = h0a; P.h0b = h0b; P.h1a = h1a; P.h1b = h1b;
    P.cnt = cnt;
    P.outp = (float*)d_out;

    // Plain launch: 512 blocks, 33.8KB LDS each -> 4 blocks/CU capacity on 256 CUs,
    // so all blocks co-resident and the per-group spin barriers are safe.
    lstm_persist<<<dim3(NBLK), dim3(NTHR), 0, stream>>>(P);
}

// Round 5
// 6936.818 us; speedup vs baseline: 1.5655x; 1.5655x over previous
//
#include <hip/hip_runtime.h>
#include <math.h>
#include <stdint.h>

#define B 1024
#define H 512
#define T_SRC 50
#define T_TGT 30
#define I_DIM 4

#define NTHR 256
#define NBLK 512
#define NGRP 16
#define GRP_BLKS 32
#define NBAR (2 * (T_SRC + T_TGT))   // 160 group barriers

typedef _Float16 half8 __attribute__((ext_vector_type(8)));
typedef float f32x4 __attribute__((ext_vector_type(4)));
typedef unsigned long long u64;
typedef u64 u64x2 __attribute__((ext_vector_type(2)));

#define GLOBAL_AS __attribute__((address_space(1)))
#define LDS_AS    __attribute__((address_space(3)))

__device__ __forceinline__ float sigm(float x) { return 1.0f / (1.0f + expf(-x)); }

__device__ __forceinline__ u64 cohl(const u64* p) {
    return __hip_atomic_load(p, __ATOMIC_RELAXED, __HIP_MEMORY_SCOPE_AGENT);
}
__device__ __forceinline__ void cohs(u64* p, u64 v) {
    __hip_atomic_store(p, v, __ATOMIC_RELAXED, __HIP_MEMORY_SCOPE_AGENT);
}

struct KParams {
    const float* x;
    const float* eWih0; const float* eb0; const float* eb1;
    const float* dWih0; const float* db0; const float* db1;
    const float* headW; const float* headb;
    const _Float16* eWhh0; const _Float16* eWih1; const _Float16* eWhh1;
    const _Float16* dWhh0; const _Float16* dWih1; const _Float16* dWhh1;
    float* c0; float* c1;
    _Float16* h0a; _Float16* h0b; _Float16* h1a; _Float16* h1b;
    uint32_t* cnt;       // [NBAR][NGRP], zeroed each call
    float* outp;         // (B, T_TGT, 4)
};

// Per-group barrier, NO cache-flushing fences. h traffic is individually
// coherent (agent-scope relaxed atomics, write-through), and __syncthreads'
// vmcnt(0) drain guarantees this block's h stores reached the coherence
// point before the arrive is issued. Weights/c stay L2-resident.
__device__ __forceinline__ void grp_barrier(uint32_t* cnt)
{
    __syncthreads();
    if (threadIdx.x == 0) {
        __hip_atomic_fetch_add(cnt, 1u, __ATOMIC_RELAXED, __HIP_MEMORY_SCOPE_AGENT);
        while (__hip_atomic_load(cnt, __ATOMIC_RELAXED, __HIP_MEMORY_SCOPE_AGENT) < GRP_BLKS)
            __builtin_amdgcn_s_sleep(2);
    }
    __syncthreads();
}

// GEMM (64 batch x 64 gate-cols, K=512*npass) + LSTM cell.
// A (h state) arrives via coherent 8B loads -> regs -> swizzled ds_write
// (byte-identical LDS layout to the verified round-2 global_load_lds path).
// B (weights) via global_load_lds, normally cached (L2-hot, read-only).
__device__ __forceinline__ void layer_step(
    char* __restrict__ smem,
    const _Float16* __restrict__ A1, const _Float16* __restrict__ W1,
    const _Float16* __restrict__ A2, const _Float16* __restrict__ W2,
    int npass,
    const float* __restrict__ xg, int xstride,   // global x rows (or null)
    const float* __restrict__ xl,                // LDS dec values (or null)
    const float* __restrict__ Wih,
    const float* __restrict__ bias,
    float* __restrict__ c_st, _Float16* __restrict__ h_out,
    int m0, int kc0,
    const size_t* __restrict__ asrc, const size_t* __restrict__ bsrc,
    const int* __restrict__ awof)
{
    const int tid = threadIdx.x;
    const int w = tid >> 6, l = tid & 63;
    const int mw = (w & 1) * 32;
    const int nw = (w >> 1) * 32;

    f32x4 acc[2][2] = {};
    const int nt = npass * 8;

    u64 R0[2][2], R1[2][2];

    auto issueA = [&](int t, u64 (&R)[2][2]) {
        const _Float16* Ap = (t < 8) ? A1 : A2;
        const int koff = (t & 7) * 64;
#pragma unroll
        for (int q = 0; q < 2; ++q) {
            const u64* ga = reinterpret_cast<const u64*>(Ap + asrc[q] + koff);
            R[q][0] = cohl(ga);
            R[q][1] = cohl(ga + 1);
        }
    };
    auto writeA = [&](u64 (&R)[2][2], char* dbase) {
#pragma unroll
        for (int q = 0; q < 2; ++q) {
            u64x2 v; v[0] = R[q][0]; v[1] = R[q][1];
            *reinterpret_cast<u64x2*>(dbase + awof[q]) = v;   // ds_write_b128
        }
    };
    auto stageB = [&](int t, char* dbase) {
        const _Float16* Wp = (t < 8) ? W1 : W2;
        const int koff = (t & 7) * 64;
#pragma unroll
        for (int q = 0; q < 2; ++q)
            __builtin_amdgcn_global_load_lds(
                (const GLOBAL_AS uint32_t*)(Wp + bsrc[q] + koff),
                (LDS_AS uint32_t*)(dbase + 8192 + (w * 2 + q) * 1024), 16, 0, 0);
    };
    auto mfma_tile = [&](const char* ab) {
        const char* bb = ab + 8192;
#pragma unroll
        for (int ks = 0; ks < 2; ++ks) {
            half8 af[2], bf[2];
#pragma unroll
            for (int f = 0; f < 2; ++f) {
                const int gg = ks * 4 + (l >> 4);
                const int m = mw + f * 16 + (l & 15);
                af[f] = *reinterpret_cast<const half8*>(ab + m * 128 + ((gg ^ (m & 7)) * 16));
                const int n = nw + f * 16 + (l & 15);
                bf[f] = *reinterpret_cast<const half8*>(bb + n * 128 + ((gg ^ (n & 7)) * 16));
            }
#pragma unroll
            for (int fm = 0; fm < 2; ++fm)
#pragma unroll
                for (int fn = 0; fn < 2; ++fn)
                    acc[fm][fn] = __builtin_amdgcn_mfma_f32_16x16x32_f16(
                        af[fm], bf[fn], acc[fm][fn], 0, 0, 0);
        }
    };

    // prologue: A depth-2 prefetch, B tile0
    stageB(0, smem);
    issueA(0, R0);
    issueA(1, R1);
    writeA(R0, smem);          // compiler waits vmcnt for A0 regs only
    __syncthreads();           // drains B0 into LDS too
    int cur = 0;
    for (int t = 0; t < nt; t += 2) {
        // even tile t: consume lds[cur]; prefetch A(t+2)->R0; write A(t+1)=R1
        {
            char* nxt = smem + (cur ^ 1) * 16384;
            if (t + 2 < nt) issueA(t + 2, R0);
            stageB(t + 1, nxt);
            mfma_tile(smem + cur * 16384);
            writeA(R1, nxt);
            __syncthreads();
            cur ^= 1;
        }
        // odd tile t+1: prefetch A(t+3)->R1; write A(t+2)=R0
        {
            char* nxt = smem + (cur ^ 1) * 16384;
            if (t + 3 < nt) issueA(t + 3, R1);
            if (t + 2 < nt) {
                stageB(t + 2, nxt);
                mfma_tile(smem + cur * 16384);
                writeA(R0, nxt);
            } else {
                mfma_tile(smem + cur * 16384);
            }
            __syncthreads();
            cur ^= 1;
        }
    }

    // stash gates (fp32) to LDS, padded stride 65
    float* Gs = reinterpret_cast<float*>(smem);
#pragma unroll
    for (int fm = 0; fm < 2; ++fm)
#pragma unroll
        for (int fn = 0; fn < 2; ++fn)
#pragma unroll
            for (int r = 0; r < 4; ++r)
                Gs[(mw + fm * 16 + (l >> 4) * 4 + r) * 65 + nw + fn * 16 + (l & 15)] =
                    acc[fm][fn][r];
    __syncthreads();

    // cell update: thread owns (m = tid&63, 4 consecutive k at kq = tid>>6)
    {
        const int em = tid & 63;
        const int ekq = tid >> 6;          // 0..3
        const int brow = m0 + em;
        const int kbase = kc0 + ekq * 4;
        float g4[4][4];
#pragma unroll
        for (int gate = 0; gate < 4; ++gate)
#pragma unroll
            for (int j = 0; j < 4; ++j)
                g4[gate][j] = Gs[em * 65 + gate * 16 + ekq * 4 + j]
                            + bias[gate * H + kbase + j];
        if (Wih != nullptr) {
            float x0, x1, x2, x3;
            if (xl != nullptr) {
                x0 = xl[em * 4 + 0]; x1 = xl[em * 4 + 1];
                x2 = xl[em * 4 + 2]; x3 = xl[em * 4 + 3];
            } else {
                const float* xr = xg + (size_t)brow * xstride;
                x0 = xr[0]; x1 = xr[1]; x2 = xr[2]; x3 = xr[3];
            }
#pragma unroll
            for (int gate = 0; gate < 4; ++gate)
#pragma unroll
                for (int j = 0; j < 4; ++j) {
                    const float* wv = &Wih[(size_t)(gate * H + kbase + j) * 4];
                    g4[gate][j] += x0 * wv[0] + x1 * wv[1] + x2 * wv[2] + x3 * wv[3];
                }
        }
        size_t cidx = (size_t)brow * H + kbase;
        f32x4 cold = *reinterpret_cast<const f32x4*>(&c_st[cidx]);
        f32x4 cnew;
        _Float16 h4[4];
#pragma unroll
        for (int j = 0; j < 4; ++j) {
            float cn = sigm(g4[1][j]) * cold[j] + sigm(g4[0][j]) * tanhf(g4[2][j]);
            cnew[j] = cn;
            h4[j] = (_Float16)(sigm(g4[3][j]) * tanhf(cn));
        }
        *reinterpret_cast<f32x4*>(&c_st[cidx]) = cnew;   // c block-private, cached
        u64 hbits;
        __builtin_memcpy(&hbits, h4, 8);
        cohs(reinterpret_cast<u64*>(h_out + cidx), hbits);  // coherent write-through
    }
}

// head: decb[row][o] = h1[m0+row,:] . headW[o,:] + headb[o]; ntile0 writes d_out
__device__ __forceinline__ void head_phase(
    const _Float16* __restrict__ h1, const float* __restrict__ headW,
    const float* __restrict__ headb, float* __restrict__ decb,
    float* __restrict__ outp, int m0, int t)
{
    const int tid = threadIdx.x;
    const int row = tid >> 2, o = tid & 3;
    const u64* hr = reinterpret_cast<const u64*>(h1 + (size_t)(m0 + row) * H);
    const float* wr = headW + o * H;
    float s = 0.f;
#pragma unroll 8
    for (int kk = 0; kk < H / 4; ++kk) {
        u64 v = cohl(hr + kk);           // h written by other blocks: coherent read
        _Float16 hv[4];
        __builtin_memcpy(hv, &v, 8);
        s += (float)hv[0] * wr[kk * 4 + 0] + (float)hv[1] * wr[kk * 4 + 1]
           + (float)hv[2] * wr[kk * 4 + 2] + (float)hv[3] * wr[kk * 4 + 3];
    }
    s += headb[o];
    decb[row * 4 + o] = s;
    if (outp != nullptr)
        outp[((size_t)(m0 + row) * T_TGT + t) * I_DIM + o] = s;
}

__global__ __launch_bounds__(NTHR, 2)
void lstm_persist(KParams P)
{
    __shared__ __align__(16) char smem[32768];
    __shared__ float decbuf[64 * 4];

    const int bx = blockIdx.x;
    // bx -> (group, ntile): CU-sharing blocks (bx, bx+256) land in different groups;
    // each XCD keeps a fixed hidden slice (weights stay L2-resident all 80 steps).
    const int sxcd = bx & 7;
    const int q = bx >> 3;
    const int lowq = q & 15;
    const int hi = (q >> 4) & 3;
    const int g = lowq ^ ((hi >> 1) << 3);
    const int ntile = sxcd * 4 + hi;
    const int m0 = g * 64;
    const int kc0 = ntile * 16;

    // staging offsets (verified round-2 swizzle mapping)
    const int tid = threadIdx.x;
    const int w = tid >> 6, l = tid & 63;
    size_t asrc[2], bsrc[2];
    int awof[2];
#pragma unroll
    for (int qq = 0; qq < 2; ++qq) {
        int rowq = (w * 2 + qq) * 8 + (l >> 3);
        int gsrc = (l & 7) ^ (rowq & 7);
        asrc[qq] = (size_t)(m0 + rowq) * H + gsrc * 8;
        int jg = (rowq >> 4) * H + kc0 + (rowq & 15);
        bsrc[qq] = (size_t)jg * H + gsrc * 8;
        awof[qq] = (w * 2 + qq) * 1024 + l * 16;
    }

    _Float16* h0[2] = {P.h0a, P.h0b};
    _Float16* h1[2] = {P.h1a, P.h1b};
    int p = 0, bar = 0;

    for (int t = 0; t < T_SRC; ++t) {
        layer_step(smem, h0[p], P.eWhh0, nullptr, nullptr, 1,
                   P.x + (size_t)t * I_DIM, T_SRC * I_DIM, nullptr,
                   P.eWih0, P.eb0, P.c0, h0[1 - p], m0, kc0, asrc, bsrc, awof);
        grp_barrier(&P.cnt[(size_t)(bar++) * NGRP + g]);
        layer_step(smem, h0[1 - p], P.eWih1, h1[p], P.eWhh1, 2,
                   nullptr, 0, nullptr, nullptr, P.eb1, P.c1, h1[1 - p],
                   m0, kc0, asrc, bsrc, awof);
        grp_barrier(&P.cnt[(size_t)(bar++) * NGRP + g]);
        p ^= 1;
    }

    for (int t = 0; t < T_TGT; ++t) {
        const float* xg = (t == 0) ? (P.x + (size_t)(T_SRC - 1) * I_DIM) : nullptr;
        const float* xl = (t == 0) ? nullptr : decbuf;
        layer_step(smem, h0[p], P.dWhh0, nullptr, nullptr, 1,
                   xg, T_SRC * I_DIM, xl, P.dWih0, P.db0, P.c0, h0[1 - p],
                   m0, kc0, asrc, bsrc, awof);
        grp_barrier(&P.cnt[(size_t)(bar++) * NGRP + g]);
        layer_step(smem, h0[1 - p], P.dWih1, h1[p], P.dWhh1, 2,
                   nullptr, 0, nullptr, nullptr, P.db1, P.c1, h1[1 - p],
                   m0, kc0, asrc, bsrc, awof);
        grp_barrier(&P.cnt[(size_t)(bar++) * NGRP + g]);
        head_phase(h1[1 - p], P.headW, P.headb, decbuf,
                   (ntile == 0) ? P.outp : nullptr, m0, t);
        __syncthreads();
        p ^= 1;
    }
}

__global__ void zero_kernel(float* __restrict__ ptr, int n)
{
    int i = blockIdx.x * blockDim.x + threadIdx.x;
    int stride = gridDim.x * blockDim.x;
    for (; i < n; i += stride) ptr[i] = 0.f;
}

__global__ void f32_to_f16(const float* __restrict__ src, _Float16* __restrict__ dst, int n)
{
    int i = blockIdx.x * blockDim.x + threadIdx.x;
    int stride = gridDim.x * blockDim.x;
    for (; i < n; i += stride) dst[i] = (_Float16)src[i];
}

extern "C" void kernel_launch(void* const* d_in, const int* in_sizes, int n_in,
                              void* d_out, int out_size, void* d_ws, size_t ws_size,
                              hipStream_t stream)
{
    const float* x        = (const float*)d_in[0];
    const float* enc_Wih0 = (const float*)d_in[1];
    const float* enc_Whh0 = (const float*)d_in[2];
    const float* enc_b0   = (const float*)d_in[3];
    const float* enc_Wih1 = (const float*)d_in[4];
    const float* enc_Whh1 = (const float*)d_in[5];
    const float* enc_b1   = (const float*)d_in[6];
    const float* dec_Wih0 = (const float*)d_in[7];
    const float* dec_Whh0 = (const float*)d_in[8];
    const float* dec_b0   = (const float*)d_in[9];
    const float* dec_Wih1 = (const float*)d_in[10];
    const float* dec_Whh1 = (const float*)d_in[11];
    const float* dec_b1   = (const float*)d_in[12];
    const float* head_W   = (const float*)d_in[13];
    const float* head_b   = (const float*)d_in[14];

    const size_t MB = 1u << 20;
    char* ws = (char*)d_ws;
    float*    c0     = (float*)(ws + 0 * MB);   // 2MB
    float*    c1     = (float*)(ws + 2 * MB);   // 2MB
    _Float16* h0a    = (_Float16*)(ws + 4 * MB);
    _Float16* h0b    = (_Float16*)(ws + 5 * MB);
    _Float16* h1a    = (_Float16*)(ws + 6 * MB);
    _Float16* h1b    = (_Float16*)(ws + 7 * MB);
    uint32_t* cnt    = (uint32_t*)(ws + 8 * MB);   // 160*16*4 = 10 KB
    _Float16* eWhh0f = (_Float16*)(ws + 9 * MB);
    _Float16* eWih1f = (_Float16*)(ws + 11 * MB);
    _Float16* eWhh1f = (_Float16*)(ws + 13 * MB);
    _Float16* dWhh0f = (_Float16*)(ws + 15 * MB);
    _Float16* dWih1f = (_Float16*)(ws + 17 * MB);
    _Float16* dWhh1f = (_Float16*)(ws + 19 * MB);

    const int WN = 4 * H * H;

    // zero c/h buffers + barrier counters
    zero_kernel<<<2048, 256, 0, stream>>>((float*)ws, (int)((8 * MB + 16384) / 4));
    f32_to_f16<<<1024, 256, 0, stream>>>(enc_Whh0, eWhh0f, WN);
    f32_to_f16<<<1024, 256, 0, stream>>>(enc_Wih1, eWih1f, WN);
    f32_to_f16<<<1024, 256, 0, stream>>>(enc_Whh1, eWhh1f, WN);
    f32_to_f16<<<1024, 256, 0, stream>>>(dec_Whh0, dWhh0f, WN);
    f32_to_f16<<<1024, 256, 0, stream>>>(dec_Wih1, dWih1f, WN);
    f32_to_f16<<<1024, 256, 0, stream>>>(dec_Whh1, dWhh1f, WN);

    KParams P;
    P.x = x;
    P.eWih0 = enc_Wih0; P.eb0 = enc_b0; P.eb1 = enc_b1;
    P.dWih0 = dec_Wih0; P.db0 = dec_b0; P.db1 = dec_b1;
    P.headW = head_W; P.headb = head_b;
    P.eWhh0 = eWhh0f; P.eWih1 = eWih1f; P.eWhh1 = eWhh1f;
    P.dWhh0 = dWhh0f; P.dWih1 = dWih1f; P.dWhh1 = dWhh1f;
    P.c0 = c0; P.c1 = c1;
    P.h0a = h0a; P.h0b = h0b; P.h1a = h1a; P.h1b = h1b;
    P.cnt = cnt;
    P.outp = (float*)d_out;

    lstm_persist<<<dim3(NBLK), dim3(NTHR), 0, stream>>>(P);
}

// Round 6
// 1702.517 us; speedup vs baseline: 6.3784x; 4.0744x over previous
//
#include <hip/hip_runtime.h>
#include <math.h>
#include <stdint.h>

#define B 1024
#define H 512
#define T_SRC 50
#define T_TGT 30
#define I_DIM 4
#define NTHR 256

typedef _Float16 half8 __attribute__((ext_vector_type(8)));
typedef float f32x4 __attribute__((ext_vector_type(4)));
typedef unsigned long long u64;

#define GLOBAL_AS __attribute__((address_space(1)))
#define LDS_AS    __attribute__((address_space(3)))

#define SCALE_F 1099511627776.0f          // 2^40
#define INV_SCALE 8.6736173798840355e-19  // 2^-60... (unused)

__device__ __forceinline__ float sigm(float x) { return 1.0f / (1.0f + expf(-x)); }

// Verified GEMM core (round 2/4): gates = A1@W1^T (+A2@W2^T) [f16 MFMA fp32-acc]
// (+ x@Wih^T + b) [fp32]; LSTM cell. Block = 64 batch rows x 64 gate cols.
// npass: 0 (skip GEMM), 1, or 2. zero_c: treat c_old as 0 (t==0).
// pH (optional LDS [64][16]): receives the block's h tile for head partials.
__device__ __forceinline__ void layer_core(
    char* smem,
    const _Float16* __restrict__ A1, const _Float16* __restrict__ W1,
    const _Float16* __restrict__ A2, const _Float16* __restrict__ W2,
    int npass, int zero_c,
    const float* __restrict__ xg, int xstride,
    const float* __restrict__ xl,
    const float* __restrict__ Wih,
    const float* __restrict__ bias,
    float* __restrict__ c_st, _Float16* __restrict__ h_out,
    _Float16* pH,
    int m0, int kc0)
{
    const int tid = threadIdx.x;
    const int w = tid >> 6, l = tid & 63;
    const int mw = (w & 1) * 32, nw = (w >> 1) * 32;

    f32x4 acc[2][2] = {};
    const int nt = npass * 8;

    size_t aoff[2], boff[2];
    int ldsw[2];
#pragma unroll
    for (int q = 0; q < 2; ++q) {
        int rowq = (w * 2 + q) * 8 + (l >> 3);
        int gsrc = (l & 7) ^ (rowq & 7);
        aoff[q] = (size_t)(m0 + rowq) * H + gsrc * 8;
        int jg = (rowq >> 4) * H + kc0 + (rowq & 15);
        boff[q] = (size_t)jg * H + gsrc * 8;
        ldsw[q] = (w * 2 + q) * 1024;
    }

    auto stage = [&](int t, int cur) {
        const _Float16* Ap = (t < 8) ? A1 : A2;
        const _Float16* Wp = (t < 8) ? W1 : W2;
        const int koff = (t & 7) * 64;
        char* dbase = smem + cur * 16384;
#pragma unroll
        for (int q = 0; q < 2; ++q) {
            __builtin_amdgcn_global_load_lds(
                (const GLOBAL_AS uint32_t*)(Ap + aoff[q] + koff),
                (LDS_AS uint32_t*)(dbase + ldsw[q]), 16, 0, 0);
            __builtin_amdgcn_global_load_lds(
                (const GLOBAL_AS uint32_t*)(Wp + boff[q] + koff),
                (LDS_AS uint32_t*)(dbase + 8192 + ldsw[q]), 16, 0, 0);
        }
    };

    if (nt > 0) {
        stage(0, 0);
        __syncthreads();
        int cur = 0;
        for (int t = 0; t < nt; ++t) {
            if (t + 1 < nt) stage(t + 1, cur ^ 1);
            const char* ab = smem + cur * 16384;
            const char* bb = ab + 8192;
#pragma unroll
            for (int ks = 0; ks < 2; ++ks) {
                half8 af[2], bf[2];
#pragma unroll
                for (int f = 0; f < 2; ++f) {
                    const int gg = ks * 4 + (l >> 4);
                    const int m = mw + f * 16 + (l & 15);
                    af[f] = *reinterpret_cast<const half8*>(ab + m * 128 + ((gg ^ (m & 7)) * 16));
                    const int n = nw + f * 16 + (l & 15);
                    bf[f] = *reinterpret_cast<const half8*>(bb + n * 128 + ((gg ^ (n & 7)) * 16));
                }
#pragma unroll
                for (int fm = 0; fm < 2; ++fm)
#pragma unroll
                    for (int fn = 0; fn < 2; ++fn)
                        acc[fm][fn] = __builtin_amdgcn_mfma_f32_16x16x32_f16(
                            af[fm], bf[fn], acc[fm][fn], 0, 0, 0);
            }
            __syncthreads();
            cur ^= 1;
        }
    }

    // stash gates (fp32) to LDS, padded stride 65
    float* Gs = reinterpret_cast<float*>(smem);
#pragma unroll
    for (int fm = 0; fm < 2; ++fm)
#pragma unroll
        for (int fn = 0; fn < 2; ++fn)
#pragma unroll
            for (int r = 0; r < 4; ++r)
                Gs[(mw + fm * 16 + (l >> 4) * 4 + r) * 65 + nw + fn * 16 + (l & 15)] =
                    acc[fm][fn][r];
    __syncthreads();

    // cell update: thread owns (row em, 4 consecutive hidden cols)
    {
        const int em = tid & 63;
        const int ekq = tid >> 6;
        const int brow = m0 + em;
        const int kbase = kc0 + ekq * 4;
        float g4[4][4];
#pragma unroll
        for (int gate = 0; gate < 4; ++gate)
#pragma unroll
            for (int j = 0; j < 4; ++j)
                g4[gate][j] = Gs[em * 65 + gate * 16 + ekq * 4 + j]
                            + bias[gate * H + kbase + j];
        if (Wih != nullptr) {
            float x0, x1, x2, x3;
            if (xl != nullptr) {
                x0 = xl[em * 4 + 0]; x1 = xl[em * 4 + 1];
                x2 = xl[em * 4 + 2]; x3 = xl[em * 4 + 3];
            } else {
                const float* xr = xg + (size_t)brow * xstride;
                x0 = xr[0]; x1 = xr[1]; x2 = xr[2]; x3 = xr[3];
            }
#pragma unroll
            for (int gate = 0; gate < 4; ++gate)
#pragma unroll
                for (int j = 0; j < 4; ++j) {
                    const float* wv = &Wih[(size_t)(gate * H + kbase + j) * 4];
                    g4[gate][j] += x0 * wv[0] + x1 * wv[1] + x2 * wv[2] + x3 * wv[3];
                }
        }
        size_t cidx = (size_t)brow * H + kbase;
        f32x4 cold;
        if (zero_c) { cold[0] = cold[1] = cold[2] = cold[3] = 0.f; }
        else        { cold = *reinterpret_cast<const f32x4*>(&c_st[cidx]); }
        f32x4 cnew;
        _Float16 h4[4];
#pragma unroll
        for (int j = 0; j < 4; ++j) {
            float cn = sigm(g4[1][j]) * cold[j] + sigm(g4[0][j]) * tanhf(g4[2][j]);
            cnew[j] = cn;
            h4[j] = (_Float16)(sigm(g4[3][j]) * tanhf(cn));
        }
        *reinterpret_cast<f32x4*>(&c_st[cidx]) = cnew;
        u64 hbits;
        __builtin_memcpy(&hbits, h4, 8);
        *reinterpret_cast<u64*>(h_out + cidx) = hbits;
        if (pH != nullptr) {
#pragma unroll
            for (int j = 0; j < 4; ++j)
                pH[em * 16 + ekq * 4 + j] = h4[j];
        }
    }
}

// Encoder pipelined dispatch d (0..50): role0 = L0(d) [if d<50], role1 = L1(d-1) [if d>=1].
__global__ __launch_bounds__(NTHR)
void enc_step(int d, const float* __restrict__ x,
              const float* __restrict__ eWih0, const float* __restrict__ eb0,
              const float* __restrict__ eb1,
              const _Float16* __restrict__ eWhh0, const _Float16* __restrict__ eWih1,
              const _Float16* __restrict__ eWhh1,
              float* __restrict__ c0, float* __restrict__ c1,
              _Float16* h0a, _Float16* h0b, _Float16* h1a, _Float16* h1b)
{
    __shared__ __align__(16) char smem[32768];
    const int bx = blockIdx.x;
    const int role = bx >> 9, sub = bx & 511;
    const int m0 = (sub & 15) * 64, kc0 = (sub >> 4) * 16;
    _Float16* h0[2] = {h0a, h0b};
    _Float16* h1[2] = {h1a, h1b};

    if (role == 0) {
        const int t = d;
        if (t >= T_SRC) return;
        const _Float16* A1 = (t == 0) ? nullptr : h0[(t - 1) & 1];
        layer_core(smem, A1, eWhh0, nullptr, nullptr, (t == 0) ? 0 : 1, (t == 0) ? 1 : 0,
                   x + (size_t)t * I_DIM, T_SRC * I_DIM, nullptr,
                   eWih0, eb0, c0, h0[t & 1], nullptr, m0, kc0);
    } else {
        const int t = d - 1;
        if (t < 0) return;
        if (t == 0)
            layer_core(smem, h0[0], eWih1, nullptr, nullptr, 1, 1,
                       nullptr, 0, nullptr, nullptr, eb1, c1, h1[0], nullptr, m0, kc0);
        else
            layer_core(smem, h0[t & 1], eWih1, h1[(t - 1) & 1], eWhh1, 2, 0,
                       nullptr, 0, nullptr, nullptr, eb1, c1, h1[t & 1], nullptr, m0, kc0);
    }
}

// Decoder layer-0 dispatch, step t. Converts head-acc(t-1) -> dec_in (+writes d_out[:,t-1,:]),
// zeroes head-acc(t) for D1(t) to fill, then the L0 GEMM+cell.
__global__ __launch_bounds__(NTHR)
void dec0_step(int t, const float* __restrict__ x,
               const float* __restrict__ dWih0, const float* __restrict__ db0,
               const float* __restrict__ headb,
               const _Float16* __restrict__ dWhh0,
               float* __restrict__ c0,
               _Float16* h0a, _Float16* h0b,
               u64* __restrict__ accA, u64* __restrict__ accB,
               float* __restrict__ outp)
{
    __shared__ __align__(16) char smem[32768];
    __shared__ float decbuf[64 * 4];
    const int sub = blockIdx.x;
    const int m0 = (sub & 15) * 64, kc0 = (sub >> 4) * 16;
    const int ntile = sub >> 4;
    const int tid = threadIdx.x;
    _Float16* h0[2] = {h0a, h0b};

    u64* accCur = (t & 1) ? accB : accA;
    u64* accPrev = (t & 1) ? accA : accB;

    const int row = tid >> 2, o = tid & 3;
    // zero current-parity acc slab for my rows (one tile per group does it)
    if (ntile == 0)
        accCur[(size_t)(m0 + row) * I_DIM + o] = 0ull;

    const float* xg = nullptr;
    const float* xl = nullptr;
    if (t == 0) {
        xg = x + (size_t)(T_SRC - 1) * I_DIM;   // decoder input 0 = x[:, -1, :]
    } else {
        long long v = (long long)accPrev[(size_t)(m0 + row) * I_DIM + o];
        float val = (float)((double)v * (1.0 / 1099511627776.0)) + headb[o];
        decbuf[tid] = val;
        if (ntile == 0)
            outp[((size_t)(m0 + row) * T_TGT + (t - 1)) * I_DIM + o] = val;
        xl = decbuf;
        __syncthreads();
    }

    const _Float16* A1 = (t == 0) ? h0[1] : h0[(t - 1) & 1];   // enc final = h0[49&1]
    layer_core(smem, A1, dWhh0, nullptr, nullptr, 1, 0,
               xg, T_SRC * I_DIM, xl, dWih0, db0, c0, h0[t & 1], nullptr, m0, kc0);
}

// Decoder layer-1 dispatch, step t. After the cell, each block adds its 16-col
// partial of the head GEMM into acc(t) as fixed-point (deterministic integer adds).
__global__ __launch_bounds__(NTHR)
void dec1_step(int t, const float* __restrict__ db1,
               const float* __restrict__ headW,
               const _Float16* __restrict__ dWih1, const _Float16* __restrict__ dWhh1,
               float* __restrict__ c1,
               _Float16* h0a, _Float16* h0b, _Float16* h1a, _Float16* h1b,
               u64* __restrict__ accA, u64* __restrict__ accB)
{
    __shared__ __align__(16) char smem[32768];
    __shared__ _Float16 pH[64 * 16];
    const int sub = blockIdx.x;
    const int m0 = (sub & 15) * 64, kc0 = (sub >> 4) * 16;
    const int tid = threadIdx.x;
    _Float16* h0[2] = {h0a, h0b};
    _Float16* h1[2] = {h1a, h1b};

    const _Float16* h1prev = (t == 0) ? h1[1] : h1[(t - 1) & 1];  // enc final = h1[49&1]
    layer_core(smem, h0[t & 1], dWih1, h1prev, dWhh1, 2, 0,
               nullptr, 0, nullptr, nullptr, db1, c1, h1[t & 1], pH, m0, kc0);
    __syncthreads();

    u64* accCur = (t & 1) ? accB : accA;
    const int em = tid >> 2, o = tid & 3;
    float s = 0.f;
#pragma unroll
    for (int j = 0; j < 16; ++j)
        s += (float)pH[em * 16 + j] * headW[(size_t)o * H + kc0 + j];
    long long q = (long long)(s * SCALE_F);
    atomicAdd(accCur + ((size_t)(m0 + em) * I_DIM + o), (u64)q);
}

// Writes d_out[:, T_TGT-1, :] from the last head accumulator.
__global__ __launch_bounds__(NTHR)
void final_out(const u64* __restrict__ accLast, const float* __restrict__ headb,
               float* __restrict__ outp)
{
    int i = blockIdx.x * blockDim.x + threadIdx.x;
    if (i < B * I_DIM) {
        int b = i >> 2, o = i & 3;
        long long v = (long long)accLast[i];
        float val = (float)((double)v * (1.0 / 1099511627776.0)) + headb[o];
        outp[((size_t)b * T_TGT + (T_TGT - 1)) * I_DIM + o] = val;
    }
}

// One dispatch converting all six hh/ih-1 weight matrices to f16 (contiguous dst).
__global__ void convert6(const float* __restrict__ s0, const float* __restrict__ s1,
                         const float* __restrict__ s2, const float* __restrict__ s3,
                         const float* __restrict__ s4, const float* __restrict__ s5,
                         _Float16* __restrict__ dst)
{
    const int WN4 = (1 << 20) / 4;
    int i = blockIdx.x * blockDim.x + threadIdx.x;
    int stride = gridDim.x * blockDim.x;
    for (; i < 6 * WN4; i += stride) {
        int seg = i / WN4;
        int off = i - seg * WN4;
        const float* sp = seg == 0 ? s0 : seg == 1 ? s1 : seg == 2 ? s2
                        : seg == 3 ? s3 : seg == 4 ? s4 : s5;
        float4 v = reinterpret_cast<const float4*>(sp)[off];
        _Float16 h4o[4] = {(_Float16)v.x, (_Float16)v.y, (_Float16)v.z, (_Float16)v.w};
        u64 bits;
        __builtin_memcpy(&bits, h4o, 8);
        reinterpret_cast<u64*>(dst)[i] = bits;
    }
}

extern "C" void kernel_launch(void* const* d_in, const int* in_sizes, int n_in,
                              void* d_out, int out_size, void* d_ws, size_t ws_size,
                              hipStream_t stream)
{
    const float* x        = (const float*)d_in[0];
    const float* enc_Wih0 = (const float*)d_in[1];
    const float* enc_Whh0 = (const float*)d_in[2];
    const float* enc_b0   = (const float*)d_in[3];
    const float* enc_Wih1 = (const float*)d_in[4];
    const float* enc_Whh1 = (const float*)d_in[5];
    const float* enc_b1   = (const float*)d_in[6];
    const float* dec_Wih0 = (const float*)d_in[7];
    const float* dec_Whh0 = (const float*)d_in[8];
    const float* dec_b0   = (const float*)d_in[9];
    const float* dec_Wih1 = (const float*)d_in[10];
    const float* dec_Whh1 = (const float*)d_in[11];
    const float* dec_b1   = (const float*)d_in[12];
    const float* head_W   = (const float*)d_in[13];
    const float* head_b   = (const float*)d_in[14];
    float* out = (float*)d_out;

    const size_t MB = 1u << 20;
    char* ws = (char*)d_ws;
    float*    c0     = (float*)(ws + 0 * MB);        // 2 MB
    float*    c1     = (float*)(ws + 2 * MB);        // 2 MB
    _Float16* h0a    = (_Float16*)(ws + 4 * MB);     // 1 MB each
    _Float16* h0b    = (_Float16*)(ws + 5 * MB);
    _Float16* h1a    = (_Float16*)(ws + 6 * MB);
    _Float16* h1b    = (_Float16*)(ws + 7 * MB);
    u64*      accA   = (u64*)(ws + 8 * MB);          // 32 KB
    u64*      accB   = (u64*)(ws + 8 * MB + 65536);  // 32 KB
    _Float16* wf16   = (_Float16*)(ws + 9 * MB);     // 6 x 2 MB contiguous
    _Float16* eWhh0f = wf16 + 0 * (1 << 20);
    _Float16* eWih1f = wf16 + 1 * (1 << 20);
    _Float16* eWhh1f = wf16 + 2 * (1 << 20);
    _Float16* dWhh0f = wf16 + 3 * (1 << 20);
    _Float16* dWih1f = wf16 + 4 * (1 << 20);
    _Float16* dWhh1f = wf16 + 5 * (1 << 20);

    convert6<<<2048, NTHR, 0, stream>>>(enc_Whh0, enc_Wih1, enc_Whh1,
                                        dec_Whh0, dec_Wih1, dec_Whh1, wf16);

    // encoder: dispatch d runs L0(d) || L1(d-1)
    for (int d = 0; d <= T_SRC; ++d)
        enc_step<<<1024, NTHR, 0, stream>>>(d, x, enc_Wih0, enc_b0, enc_b1,
                                            eWhh0f, eWih1f, eWhh1f,
                                            c0, c1, h0a, h0b, h1a, h1b);

    // decoder: 2 dispatches per step; head folded into dec1 (fixed-point atomics)
    for (int t = 0; t < T_TGT; ++t) {
        dec0_step<<<512, NTHR, 0, stream>>>(t, x, dec_Wih0, dec_b0, head_b,
                                            dWhh0f, c0, h0a, h0b, accA, accB, out);
        dec1_step<<<512, NTHR, 0, stream>>>(t, dec_b1, head_W, dWih1f, dWhh1f,
                                            c1, h0a, h0b, h1a, h1b, accA, accB);
    }
    final_out<<<(B * I_DIM + NTHR - 1) / NTHR, NTHR, 0, stream>>>(
        (T_TGT - 1) & 1 ? accB : accA, head_b, out);
}